// Round 7
// baseline (24.736 us; speedup 1.0000x reference)
//
#include <hip/hip_runtime.h>
#include <math.h>

#define LMAX  50
#define NWAVE 2048    // 512 blocks x 4 waves; wave handles elements wid, wid+2048

typedef short bf16x8 __attribute__((ext_vector_type(8)));
typedef float f32x4  __attribute__((ext_vector_type(4)));
union bfu { bf16x8 v; unsigned u[4]; int s[4]; };

// packed f32 pair -> 2x bf16 (RNE), single VALU instr; lo -> low 16 bits
__device__ __forceinline__ unsigned cvt_pk(float lo, float hi) {
    unsigned r;
    asm("v_cvt_pk_bf16_f32 %0, %1, %2" : "=v"(r) : "v"(lo), "v"(hi));
    return r;
}
__device__ __forceinline__ bf16x8 cvt8f(float4 a, float4 b) {
    bfu r;
    r.u[0] = cvt_pk(a.x, a.y); r.u[1] = cvt_pk(a.z, a.w);
    r.u[2] = cvt_pk(b.x, b.y); r.u[3] = cvt_pk(b.z, b.w);
    return r.v;
}
__device__ __forceinline__ float bf2f(short s) {
    union { unsigned u; float f; } v; v.u = ((unsigned)(unsigned short)s) << 16;
    return v.f;
}

// Swapped-operand dataflow: D1 = W1^T @ X^T (rows = hidden n, cols = neighbor r).
// A-frag and B-frag share the lane->(idx16, k) map, so weight frags staged as
// M[k][col] serve directly as A = M^T. C-layout: col=l15, row n = 16nt+4g+reg.
__global__ __launch_bounds__(256, 2) void graphrec_k(
    const float* __restrict__ u_table, const float* __restrict__ i_table,
    const float* __restrict__ W1, const float* __restrict__ b1,
    const float* __restrict__ W2, const float* __restrict__ b2,
    const float* __restrict__ W3, const float* __restrict__ b3,
    const int* __restrict__ nodes, const int* __restrict__ neighbors,
    const int* __restrict__ lengths, float* __restrict__ out)
{
    __shared__ __attribute__((aligned(16))) short WF[24][64][8];   // 24.5 KB

    const int tid = threadIdx.x;
    const int w = tid >> 6, lane = tid & 63;
    const int l15 = lane & 15, g = lane >> 4, g8 = g * 8;

    // stage frags: f = ks*4+nt for W1 (ks 0..3; 2..3 = node half k=64..127),
    // f = 16 + ks*4+nt2 for W2. lane(l15,g) holds M[ks*32+g8+i][nt*16+l15].
    for (int f = w; f < 24; f += 4) {
        const float* Ws = (f < 16) ? W1 : W2;
        const int fi = (f < 16) ? f : f - 16;
        const int ks = fi >> 2, nt = fi & 3;
        const float* p = Ws + (ks * 32 + g8) * 64 + nt * 16 + l15;
        bfu r;
        r.u[0] = cvt_pk(p[0],   p[64]);
        r.u[1] = cvt_pk(p[128], p[192]);
        r.u[2] = cvt_pk(p[256], p[320]);
        r.u[3] = cvt_pk(p[384], p[448]);
        *(bf16x8*)&WF[f][lane][0] = r.v;
    }
    __syncthreads();

    // persistent VGPR: W1^T neighbor-half A-frags only (32 VGPR)
    bf16x8 w1nf[2][4];
    #pragma unroll
    for (int ks = 0; ks < 2; ++ks)
        #pragma unroll
        for (int nt = 0; nt < 4; ++nt)
            w1nf[ks][nt] = *(const bf16x8*)&WF[ks * 4 + nt][lane][0];

    float4 w3v[4];   // row layout: w3[16nt2 + 4g + reg]
    #pragma unroll
    for (int nt = 0; nt < 4; ++nt)
        w3v[nt] = *(const float4*)(W3 + nt * 16 + 4 * g);

    // bpermute source lanes for the H1^T exchange (derivation in comments below)
    const int s0 = l15 + 16 * ((2 * g) & 3);
    const int s1 = l15 + 16 * ((2 * g + 1) & 3);

    const int wid = blockIdx.x * 4 + w;
    const int bb[2] = { wid, wid + NWAVE };
    int len[2], ntl[2], nd[2], idx[2][4];
    #pragma unroll
    for (int e = 0; e < 2; ++e) {
        len[e] = lengths[bb[e]];
        nd[e]  = nodes[bb[e]];
        ntl[e] = (len[e] + 15) >> 4;
        #pragma unroll
        for (int t = 0; t < 4; ++t) {
            int r = t * 16 + l15; if (r >= len[e]) r = len[e] - 1;
            idx[e][t] = (t < ntl[e]) ? neighbors[bb[e] * LMAX + r] : 0;
        }
    }

    float4 LA[2][4];   // 1-deep rolling x-gather (f32, in flight during tile)
    #define ISSUE(e, t) { \
        const float* xp = i_table + (size_t)idx[e][t] * 64 + g8; \
        LA[e][0] = *(const float4*)(xp); \
        LA[e][1] = *(const float4*)(xp + 4); \
        LA[e][2] = *(const float4*)(xp + 32); \
        LA[e][3] = *(const float4*)(xp + 36); \
    }
    ISSUE(0, 0) ISSUE(1, 0)          // ntl >= 1 always

    // node half of layer 1: hn[n][*] = b1[n] + sum_k W1[64+k][n] xu[k]
    // (B = broadcast xu frag -> D independent of col; rows n = 16nt+4g+reg)
    f32x4 hn[2][4];
    {
        float4 UA[2][4];
        #pragma unroll
        for (int e = 0; e < 2; ++e) {
            const float* up = u_table + (size_t)nd[e] * 64 + g8;
            UA[e][0] = *(const float4*)(up);
            UA[e][1] = *(const float4*)(up + 4);
            UA[e][2] = *(const float4*)(up + 32);
            UA[e][3] = *(const float4*)(up + 36);
        }
        #pragma unroll
        for (int e = 0; e < 2; ++e) {
            bf16x8 axu0 = cvt8f(UA[e][0], UA[e][1]);
            bf16x8 axu1 = cvt8f(UA[e][2], UA[e][3]);
            #pragma unroll
            for (int nt = 0; nt < 4; ++nt) {
                float4 bv = *(const float4*)(b1 + nt * 16 + 4 * g);
                f32x4 c = { bv.x, bv.y, bv.z, bv.w };
                c = __builtin_amdgcn_mfma_f32_16x16x32_bf16(
                        *(const bf16x8*)&WF[8  + nt][lane][0], axu0, c, 0, 0, 0);
                c = __builtin_amdgcn_mfma_f32_16x16x32_bf16(
                        *(const bf16x8*)&WF[12 + nt][lane][0], axu1, c, 0, 0, 0);
                hn[e][nt] = c;
            }
        }
    }
    // b3 shifts all logits equally -> softmax-invariant, skip.

    float m[2]    = { -INFINITY, -INFINITY };
    float ssum[2] = { 0.f, 0.f };            // per-lane partial (row l15)
    float accW[2][16];
    #pragma unroll
    for (int e = 0; e < 2; ++e)
        #pragma unroll
        for (int i = 0; i < 16; ++i) accW[e][i] = 0.f;

    bf16x8 af0[2], af1[2];

    #pragma unroll
    for (int t = 0; t < 4; ++t) {
        #pragma unroll
        for (int e = 0; e < 2; ++e) if (t < ntl[e]) {
            af0[e] = cvt8f(LA[e][0], LA[e][1]);   // X[l15][g8..g8+7]   (k 0..31)
            af1[e] = cvt8f(LA[e][2], LA[e][3]);   // X[l15][32+g8..]    (k 32..63)
        }
        if (t < 3) {
            #pragma unroll
            for (int e = 0; e < 2; ++e) if (t + 1 < ntl[e]) ISSUE(e, t + 1);
        }

        // ---- layer 1 (neighbor half): D1 = W1n^T @ X^T + hn ----
        f32x4 p1[2][4];
        #pragma unroll
        for (int e = 0; e < 2; ++e) if (t < ntl[e]) {
            #pragma unroll
            for (int nt = 0; nt < 4; ++nt) {
                f32x4 c = hn[e][nt];
                c = __builtin_amdgcn_mfma_f32_16x16x32_bf16(w1nf[0][nt], af0[e], c, 0, 0, 0);
                c = __builtin_amdgcn_mfma_f32_16x16x32_bf16(w1nf[1][nt], af1[e], c, 0, 0, 0);
                p1[e][nt] = c;
            }
        }

        // ---- relu + pack + in-register exchange -> B-frags of relu(H1^T) ----
        // Held:  lane(l15,g), Q[nt][pr] = H^T[16nt+4g+2pr+{0,1}][l15]
        // Need:  B u32 reg rr (ks): H^T[32ks+8g+2rr+{0,1}][l15]
        //   nt_src = 2ks + (g>>1); g_src = (2g + (rr>>1))&3; pr_src = rr&1
        bfu B[2][2];
        #pragma unroll
        for (int e = 0; e < 2; ++e) if (t < ntl[e]) {
            int Q[4][2];
            #pragma unroll
            for (int nt = 0; nt < 4; ++nt) {
                Q[nt][0] = (int)cvt_pk(fmaxf(p1[e][nt][0], 0.f), fmaxf(p1[e][nt][1], 0.f));
                Q[nt][1] = (int)cvt_pk(fmaxf(p1[e][nt][2], 0.f), fmaxf(p1[e][nt][3], 0.f));
            }
            #pragma unroll
            for (int ks = 0; ks < 2; ++ks)
                #pragma unroll
                for (int rr = 0; rr < 4; ++rr) {
                    const int sl = (rr & 2) ? s1 : s0;
                    const int v0 = __shfl(Q[2 * ks + 0][rr & 1], sl);
                    const int v1 = __shfl(Q[2 * ks + 1][rr & 1], sl);
                    B[e][ks].s[rr] = (g & 2) ? v1 : v0;
                }
        }

        // ---- layer 2 + logits + online softmax + weighted partials ----
        #pragma unroll
        for (int e = 0; e < 2; ++e) if (t < ntl[e]) {
            float ls = 0.f;
            #pragma unroll
            for (int nt2 = 0; nt2 < 4; ++nt2) {
                float4 bv = *(const float4*)(b2 + nt2 * 16 + 4 * g);
                f32x4 c = { bv.x, bv.y, bv.z, bv.w };
                c = __builtin_amdgcn_mfma_f32_16x16x32_bf16(
                        *(const bf16x8*)&WF[16 + nt2][lane][0], B[e][0].v, c, 0, 0, 0);
                c = __builtin_amdgcn_mfma_f32_16x16x32_bf16(
                        *(const bf16x8*)&WF[20 + nt2][lane][0], B[e][1].v, c, 0, 0, 0);
                ls = fmaf(fmaxf(c[0], 0.f), w3v[nt2].x, ls);
                ls = fmaf(fmaxf(c[1], 0.f), w3v[nt2].y, ls);
                ls = fmaf(fmaxf(c[2], 0.f), w3v[nt2].z, ls);
                ls = fmaf(fmaxf(c[3], 0.f), w3v[nt2].w, ls);
            }
            ls += __shfl_xor(ls, 16);
            ls += __shfl_xor(ls, 32);            // logit[r=l15], replicated over g

            const int rabs = t * 16 + l15;
            const float lgv = (rabs < len[e]) ? ls : -INFINITY;
            float tm = fmaxf(lgv, __shfl_xor(lgv, 1));
            tm = fmaxf(tm, __shfl_xor(tm, 2));
            tm = fmaxf(tm, __shfl_xor(tm, 4));
            tm = fmaxf(tm, __shfl_xor(tm, 8));   // wave-uniform tile max
            if (tm > m[e]) {                     // first tile: exp(-inf)=0
                const float sc = __expf(m[e] - tm);
                ssum[e] *= sc;
                #pragma unroll
                for (int i = 0; i < 16; ++i) accW[e][i] *= sc;
                m[e] = tm;
            }
            const float er = __expf(lgv - m[e]); // e for THIS lane's row (masked->0)
            ssum[e] += er;
            #pragma unroll
            for (int i = 0; i < 8; ++i) {
                accW[e][i]     = fmaf(er, bf2f(af0[e][i]), accW[e][i]);
                accW[e][8 + i] = fmaf(er, bf2f(af1[e][i]), accW[e][8 + i]);
            }
        }
    }
    #undef ISSUE

    // ---- finalize: reduce over the 16 rows (l15), write 64 dims ----
    #pragma unroll
    for (int e = 0; e < 2; ++e) {
        #pragma unroll
        for (int i = 0; i < 16; ++i) {
            accW[e][i] += __shfl_xor(accW[e][i], 1);
            accW[e][i] += __shfl_xor(accW[e][i], 2);
            accW[e][i] += __shfl_xor(accW[e][i], 4);
            accW[e][i] += __shfl_xor(accW[e][i], 8);
        }
        float ss = ssum[e];
        ss += __shfl_xor(ss, 1);
        ss += __shfl_xor(ss, 2);
        ss += __shfl_xor(ss, 4);
        ss += __shfl_xor(ss, 8);
        const float inv = 1.f / ss;
        if (l15 == 0) {
            const int b = bb[e];
            float4 o0 = make_float4(accW[e][0]  * inv, accW[e][1]  * inv, accW[e][2]  * inv, accW[e][3]  * inv);
            float4 o1 = make_float4(accW[e][4]  * inv, accW[e][5]  * inv, accW[e][6]  * inv, accW[e][7]  * inv);
            float4 o2 = make_float4(accW[e][8]  * inv, accW[e][9]  * inv, accW[e][10] * inv, accW[e][11] * inv);
            float4 o3 = make_float4(accW[e][12] * inv, accW[e][13] * inv, accW[e][14] * inv, accW[e][15] * inv);
            *(float4*)(out + b * 64 +      g8)     = o0;
            *(float4*)(out + b * 64 +      g8 + 4) = o1;
            *(float4*)(out + b * 64 + 32 + g8)     = o2;
            *(float4*)(out + b * 64 + 32 + g8 + 4) = o3;
        }
    }
}

extern "C" void kernel_launch(void* const* d_in, const int* in_sizes, int n_in,
                              void* d_out, int out_size, void* d_ws, size_t ws_size,
                              hipStream_t stream) {
    const float* u_table   = (const float*)d_in[0];
    const float* i_table   = (const float*)d_in[1];
    const float* W1        = (const float*)d_in[2];
    const float* b1        = (const float*)d_in[3];
    const float* W2        = (const float*)d_in[4];
    const float* b2        = (const float*)d_in[5];
    const float* W3        = (const float*)d_in[6];
    const float* b3        = (const float*)d_in[7];
    const int*   nodes     = (const int*)d_in[8];
    const int*   neighbors = (const int*)d_in[9];
    const int*   lengths   = (const int*)d_in[10];
    float* out = (float*)d_out;

    graphrec_k<<<dim3(NWAVE / 4), dim3(256), 0, stream>>>(
        u_table, i_table, W1, b1, W2, b2, W3, b3, nodes, neighbors, lengths, out);
}